// Round 8
// baseline (122.741 us; speedup 1.0000x reference)
//
#include <hip/hip_runtime.h>
#include <stdint.h>

#define B_   32
#define DIM_ 16
#define H_   128
#define DM_  256
#define NH_  8
#define WP_  32     // DM/NH
#define C3_  384    // 3*NH*DIM

typedef short bf16x8 __attribute__((ext_vector_type(8)));
typedef float f32x4  __attribute__((ext_vector_type(4)));

__device__ __forceinline__ unsigned short f2bfu(float v) {
    unsigned int x = __float_as_uint(v);
    x += 0x7fffu + ((x >> 16) & 1u);   // RNE
    return (unsigned short)(x >> 16);
}
__device__ __forceinline__ unsigned cvtpk(float lo, float hi) {
    unsigned r;
    asm("v_cvt_pk_bf16_f32 %0, %1, %2" : "=v"(r) : "v"(lo), "v"(hi));
    return r;
}
// async global->LDS, 16B per lane; lds dest = wave-uniform base + lane*16
__device__ __forceinline__ void gl_lds16(const void* g, void* l) {
    __builtin_amdgcn_global_load_lds(
        (const __attribute__((address_space(1))) unsigned int*)g,
        (__attribute__((address_space(3))) unsigned int*)l, 16, 0, 0);
}

// ============================================================================
// Kernel 1 (v5): fused conv1+conv2, tap-sharing + LDS weights, 4h/thread.
// v4 post-mortem: store-coalescing theory falsified; bottleneck is MLP/TLP
// (1024 blocks = 4/CU, long serial per-thread chain). v5: 2048 blocks
// (8/CU), 4h per thread (8-row x tile, 21 MAC/out), Q/K scatter stores
// ([o][h][wp], v3b-style), V direct 8B stores ([o][wp][h], attn-compatible).
// Grid: 32 b * 16 g * 4 ht = 2048 blocks, 256 thr (8 hl x 32 wp).
// ============================================================================
__global__ __launch_bounds__(256) void conv_kernel(
    const float* __restrict__ x, const float* __restrict__ w1,
    const float* __restrict__ w2, unsigned short* __restrict__ y2)
{
    __shared__ float wlds[24 * 16];   // [oc][0..4]=w1, [5..12]=w2, rest pad

    const int bid = blockIdx.x;
    const int ht = bid & 3;
    const int g  = (bid >> 2) & 15;
    const int b  = bid >> 6;
    const int tid = threadIdx.x;
    const int wp = tid & 31;
    const int hl = tid >> 5;          // 0..7
    const int h0 = ht * 32 + hl * 4;  // first output h of this thread

    // ---- one-time weight staging (block-uniform); 384 entries, 256 threads ----
    for (int i = tid; i < 384; i += 256) {
        const int oc = i >> 4, ix = i & 15;
        const int o = g * 24 + oc;
        float v = 0.f;
        if (ix < 5)       v = w1[o * 5 + ix];
        else if (ix < 13) v = w2[o * 8 + (ix - 5)];
        wlds[i] = v;
    }

    const float* xbase = x + ((size_t)(b * DIM_ + g) * H_) * DM_ + wp * 8;

    float xr[8][8];
    #pragma unroll
    for (int r = 0; r < 8; ++r) {
        const int hr = h0 - 2 + r;
        if (hr >= 0 && hr < H_) {
            const float4* p = (const float4*)(xbase + (size_t)hr * DM_);
            float4 a = p[0], c = p[1];
            xr[r][0] = a.x; xr[r][1] = a.y; xr[r][2] = a.z; xr[r][3] = a.w;
            xr[r][4] = c.x; xr[r][5] = c.y; xr[r][6] = c.z; xr[r][7] = c.w;
        } else {
            #pragma unroll
            for (int j = 0; j < 8; ++j) xr[r][j] = 0.f;
        }
    }
    __syncthreads();

    unsigned short* ybQK = y2 + (((size_t)(b * C3_ + g * 24)) * H_ + h0) * WP_ + wp;

    for (int oc = 0; oc < 24; ++oc) {
        const int o = g * 24 + oc;
        const float* wo_ = &wlds[oc * 16];
        float w1r[5], w2r[8];
        {
            float4 a = *(const float4*)(wo_);       // w1[0..3]
            float4 c = *(const float4*)(wo_ + 4);   // w1[4], w2[0..2]
            float4 d = *(const float4*)(wo_ + 8);   // w2[3..6]
            w1r[0] = a.x; w1r[1] = a.y; w1r[2] = a.z; w1r[3] = a.w;
            w1r[4] = c.x;
            w2r[0] = c.y; w2r[1] = c.z; w2r[2] = c.w;
            w2r[3] = d.x; w2r[4] = d.y; w2r[5] = d.z; w2r[6] = d.w;
            w2r[7] = wo_[12];
        }

        float u[8];
        #pragma unroll
        for (int r = 0; r < 8; ++r) {
            float s = w2r[0] * xr[r][0];
            #pragma unroll
            for (int j = 1; j < 8; ++j) s = fmaf(w2r[j], xr[r][j], s);
            u[r] = s;
        }

        unsigned short yv[4];
        #pragma unroll
        for (int hh = 0; hh < 4; ++hh) {
            float y = w1r[0] * u[hh];
            #pragma unroll
            for (int t = 1; t < 5; ++t) y = fmaf(w1r[t], u[hh + t], y);
            yv[hh] = f2bfu(y);
        }

        if (o >= 256) {
            // V: 8B store, layout [o][wp][h]
            uint2 pk;
            pk.x = (unsigned)yv[0] | ((unsigned)yv[1] << 16);
            pk.y = (unsigned)yv[2] | ((unsigned)yv[3] << 16);
            *(uint2*)(y2 + ((size_t)(b * C3_ + o) * 32 + wp) * 128 + h0) = pk;
        } else {
            // Q/K: scatter 2B stores, layout [o][h][wp]
            #pragma unroll
            for (int hh = 0; hh < 4; ++hh)
                ybQK[(size_t)oc * (H_ * WP_) + hh * WP_] = yv[hh];
        }
    }
}

// ============================================================================
// Kernel 2: MFMA attention per (b, ch). Unchanged from round 7 (known-good;
// V read from [o][wp][h], Q/K from [o][h][wp]).
// ============================================================================
__global__ __launch_bounds__(256) void attn_kernel(
    const unsigned short* __restrict__ y2, unsigned short* __restrict__ z)
{
    __shared__ __align__(16) unsigned char sm[40960];

    const int tid = threadIdx.x;
    const int ch = blockIdx.x & 127, b = blockIdx.x >> 7;
    const size_t base = ((size_t)(b * C3_ + ch)) * 4096;
    const uint4* qg = (const uint4*)(y2 + base);
    const uint4* kg = (const uint4*)(y2 + base + 128 * 4096);
    const uint4* vg = (const uint4*)(y2 + base + 256 * 4096);

    #pragma unroll
    for (int r = 0; r < 2; ++r) {
        const int ci  = tid + r * 256;
        const int row = ci >> 2;
        const int c   = ci & 3;
        const int cx  = c ^ ((row >> 1) & 3);
        *(uint4*)(sm + row * 64 + cx * 16)        = qg[ci];
        *(uint4*)(sm + 8192 + row * 64 + cx * 16) = kg[ci];
        // V: global [32 wp][128 h] -> Vt LDS [d=wp][k=h], chunk ^ ((d&7)<<4)
        const int vd = ci >> 4;        // 0..31
        const int vhc = ci & 15;       // 16B chunk along h
        *(uint4*)(sm + 32768 + vd * 256 + ((vhc * 16) ^ ((vd & 7) << 4))) = vg[ci];
    }
    __syncthreads();

    const int l  = tid & 63, wv = tid >> 6;
    const int lm = l & 15,  lk = l >> 4;

    bf16x8 qf[2];
    #pragma unroll
    for (int t = 0; t < 2; ++t) {
        const int q = (wv * 2 + t) * 16 + lm;
        qf[t] = *(const bf16x8*)(sm + q * 64 + ((lk ^ ((q >> 1) & 3)) << 4));
    }
    f32x4 acc[8][2];
    #pragma unroll
    for (int rt = 0; rt < 8; ++rt) {
        acc[rt][0] = 0; acc[rt][1] = 0;
    }
    #pragma unroll
    for (int rt = 0; rt < 8; ++rt) {
        const int kr = rt * 16 + lm;
        bf16x8 kf = *(const bf16x8*)(sm + 8192 + kr * 64 + ((lk ^ ((kr >> 1) & 3)) << 4));
        acc[rt][0] = __builtin_amdgcn_mfma_f32_16x16x32_bf16(kf, qf[0], acc[rt][0], 0, 0, 0);
        acc[rt][1] = __builtin_amdgcn_mfma_f32_16x16x32_bf16(kf, qf[1], acc[rt][1], 0, 0, 0);
    }

    const float Cc = 0.17677669529663687f * 1.4426950408889634f;
    float inv[2];
    #pragma unroll
    for (int t = 0; t < 2; ++t) {
        float m = acc[0][t][0];
        #pragma unroll
        for (int rt = 0; rt < 8; ++rt)
            #pragma unroll
            for (int rg = 0; rg < 4; ++rg) m = fmaxf(m, acc[rt][t][rg]);
        m = fmaxf(m, __shfl_xor(m, 16));
        m = fmaxf(m, __shfl_xor(m, 32));
        float s = 0.f;
        #pragma unroll
        for (int rt = 0; rt < 8; ++rt)
            #pragma unroll
            for (int rg = 0; rg < 4; ++rg) {
                float p = exp2f((acc[rt][t][rg] - m) * Cc);
                acc[rt][t][rg] = p; s += p;
            }
        s += __shfl_xor(s, 16);
        s += __shfl_xor(s, 32);
        inv[t] = 1.0f / s;
    }

    __syncthreads();

    #pragma unroll
    for (int t = 0; t < 2; ++t) {
        const int q = (wv * 2 + t) * 16 + lm;
        #pragma unroll
        for (int rt = 0; rt < 8; ++rt) {
            unsigned u0 = cvtpk(acc[rt][t][0] * inv[t], acc[rt][t][1] * inv[t]);
            unsigned u1 = cvtpk(acc[rt][t][2] * inv[t], acc[rt][t][3] * inv[t]);
            const int kb = rt * 32 + lk * 8;
            *(uint2*)(sm + q * 256 + (kb ^ ((q & 7) << 4))) = make_uint2(u0, u1);
        }
    }
    __syncthreads();

    f32x4 o[2][2];
    o[0][0] = 0; o[0][1] = 0; o[1][0] = 0; o[1][1] = 0;
    #pragma unroll
    for (int kc = 0; kc < 4; ++kc) {
        const int cb = kc * 64 + lk * 16;
        bf16x8 av[2], bp[2];
        #pragma unroll
        for (int dt = 0; dt < 2; ++dt) {
            const int d = dt * 16 + lm;
            av[dt] = *(const bf16x8*)(sm + 32768 + d * 256 + (cb ^ ((d & 7) << 4)));
        }
        #pragma unroll
        for (int t = 0; t < 2; ++t) {
            const int q = (wv * 2 + t) * 16 + lm;
            bp[t] = *(const bf16x8*)(sm + q * 256 + (cb ^ ((q & 7) << 4)));
        }
        #pragma unroll
        for (int dt = 0; dt < 2; ++dt)
            #pragma unroll
            for (int t = 0; t < 2; ++t)
                o[dt][t] = __builtin_amdgcn_mfma_f32_16x16x32_bf16(av[dt], bp[t], o[dt][t], 0, 0, 0);
    }

    const int dd = ch >> 3, nn = ch & 7;
    unsigned short* zb = z + ((size_t)(b * DIM_ + dd)) * (H_ * DM_);
    #pragma unroll
    for (int dt = 0; dt < 2; ++dt)
        #pragma unroll
        for (int t = 0; t < 2; ++t) {
            const int q  = (wv * 2 + t) * 16 + lm;
            const int d0 = dt * 16 + lk * 4;
            unsigned u0 = cvtpk(o[dt][t][0], o[dt][t][1]);
            unsigned u1 = cvtpk(o[dt][t][2], o[dt][t][3]);
            *(uint2*)(zb + (size_t)q * DM_ + nn * 32 + d0) = make_uint2(u0, u1);
        }
}

// ============================================================================
// Kernel 3: W -> bf16 hi/lo split. Unchanged.
// ============================================================================
__global__ __launch_bounds__(256) void prep_w(
    const float* __restrict__ w, unsigned short* __restrict__ wh,
    unsigned short* __restrict__ wl)
{
    const int i = blockIdx.x * 1024 + threadIdx.x * 4;
    float4 v = *(const float4*)(w + i);
    float vv[4] = { v.x, v.y, v.z, v.w };
    unsigned short h[4], lo[4];
    #pragma unroll
    for (int j = 0; j < 4; ++j) {
        h[j] = f2bfu(vv[j]);
        float hf = __uint_as_float(((unsigned)h[j]) << 16);
        lo[j] = f2bfu(vv[j] - hf);
    }
    *(uint2*)(wh + i) = make_uint2((unsigned)h[0] | ((unsigned)h[1] << 16),
                                   (unsigned)h[2] | ((unsigned)h[3] << 16));
    *(uint2*)(wl + i) = make_uint2((unsigned)lo[0] | ((unsigned)lo[1] << 16),
                                   (unsigned)lo[2] | ((unsigned)lo[3] << 16));
}

// ============================================================================
// Kernel 4: MFMA out-projection. Unchanged (known-good).
// ============================================================================
__global__ __launch_bounds__(256) void proj_kernel(
    const unsigned short* __restrict__ zz, const unsigned short* __restrict__ wh,
    const unsigned short* __restrict__ wl, const float* __restrict__ bias,
    float* __restrict__ out)
{
    __shared__ __align__(16) unsigned char sm[65536];   // 2 bufs x 32KB
    const int tid = threadIdx.x;
    const int l = tid & 63, wv = tid >> 6, lm = l & 15, lk = l >> 4;
    const unsigned short* zs = zz + (size_t)blockIdx.x * 32768;

    const int g_off = (tid >> 2) * 256 + (tid & 3) * 8;   // elements within W
    const int lds_wv = wv * 1024;                          // wave-uniform lane base

    const int arow0 = wv * 32 + lm;

    f32x4 acc[2][16];
    #pragma unroll
    for (int t = 0; t < 2; ++t)
        #pragma unroll
        for (int nt = 0; nt < 16; ++nt) acc[t][nt] = 0;

    bf16x8 areg[2][2];

    #pragma unroll
    for (int i = 0; i < 8; ++i) {
        const unsigned short* g = (i < 4 ? wh : wl) + g_off + (i & 3) * 16384;
        gl_lds16(g, sm + i * 4096 + lds_wv);
    }
    #pragma unroll
    for (int t = 0; t < 2; ++t)
        areg[0][t] = *(const bf16x8*)(zs + (size_t)(arow0 + t * 16) * 256 + lk * 8);

    __syncthreads();

    #pragma unroll
    for (int kc = 0; kc < 8; ++kc) {
        const int buf = kc & 1;
        if (kc < 7) {
            #pragma unroll
            for (int i = 0; i < 8; ++i) {
                const unsigned short* g = (i < 4 ? wh : wl) + g_off + (i & 3) * 16384 + (kc + 1) * 32;
                gl_lds16(g, sm + (buf ^ 1) * 32768 + i * 4096 + lds_wv);
            }
            #pragma unroll
            for (int t = 0; t < 2; ++t)
                areg[buf ^ 1][t] = *(const bf16x8*)(zs + (size_t)(arow0 + t * 16) * 256 + (kc + 1) * 32 + lk * 8);
        }
        #pragma unroll
        for (int ph = 0; ph < 2; ++ph)
            #pragma unroll
            for (int nt = 0; nt < 16; ++nt) {
                bf16x8 bf = *(const bf16x8*)(sm + buf * 32768 + ph * 16384 + nt * 1024 + lm * 64 + lk * 16);
                acc[0][nt] = __builtin_amdgcn_mfma_f32_16x16x32_bf16(areg[buf][0], bf, acc[0][nt], 0, 0, 0);
                acc[1][nt] = __builtin_amdgcn_mfma_f32_16x16x32_bf16(areg[buf][1], bf, acc[1][nt], 0, 0, 0);
            }
        __syncthreads();
    }

    float* ob = out + (size_t)blockIdx.x * 32768;
    #pragma unroll
    for (int t = 0; t < 2; ++t)
        #pragma unroll
        for (int nt = 0; nt < 16; ++nt) {
            const float bv = bias[nt * 16 + lm];
            #pragma unroll
            for (int rg = 0; rg < 4; ++rg)
                ob[(size_t)(wv * 32 + t * 16 + lk * 4 + rg) * 256 + nt * 16 + lm] = acc[t][nt][rg] + bv;
        }
}

// ============================================================================
extern "C" void kernel_launch(void* const* d_in, const int* in_sizes, int n_in,
                              void* d_out, int out_size, void* d_ws, size_t ws_size,
                              hipStream_t stream)
{
    const float* x  = (const float*)d_in[0];
    const float* w1 = (const float*)d_in[1];
    const float* w2 = (const float*)d_in[2];
    const float* wo = (const float*)d_in[3];
    const float* wb = (const float*)d_in[4];
    float* out = (float*)d_out;

    unsigned short* y2 = (unsigned short*)d_ws;                    // 100,663,296 B
    unsigned short* zz = y2 + (size_t)B_ * C3_ * H_ * WP_;         // + 33,554,432 B
    unsigned short* wh = y2;                                       // overlays dead y2 (after attn)
    unsigned short* wl = y2 + 65536;

    conv_kernel<<<dim3(2048), dim3(256), 0, stream>>>(x, w1, w2, y2);
    attn_kernel<<<dim3(4096), dim3(256), 0, stream>>>(y2, zz);
    prep_w<<<dim3(64), dim3(256), 0, stream>>>(wo, wh, wl);
    proj_kernel<<<dim3(512), dim3(256), 0, stream>>>(zz, wh, wl, wb, out);
}

// Round 9
// 114.236 us; speedup vs baseline: 1.0745x; 1.0745x over previous
//
#include <hip/hip_runtime.h>
#include <stdint.h>

#define B_   32
#define DIM_ 16
#define H_   128
#define DM_  256
#define NH_  8
#define WP_  32     // DM/NH
#define C3_  384    // 3*NH*DIM

typedef short bf16x8 __attribute__((ext_vector_type(8)));
typedef float f32x4  __attribute__((ext_vector_type(4)));

__device__ __forceinline__ unsigned short f2bfu(float v) {
    unsigned int x = __float_as_uint(v);
    x += 0x7fffu + ((x >> 16) & 1u);   // RNE
    return (unsigned short)(x >> 16);
}
__device__ __forceinline__ unsigned cvtpk(float lo, float hi) {
    unsigned r;
    asm("v_cvt_pk_bf16_f32 %0, %1, %2" : "=v"(r) : "v"(lo), "v"(hi));
    return r;
}
// async global->LDS, 16B per lane; lds dest = wave-uniform base + lane*16
__device__ __forceinline__ void gl_lds16(const void* g, void* l) {
    __builtin_amdgcn_global_load_lds(
        (const __attribute__((address_space(1))) unsigned int*)g,
        (__attribute__((address_space(3))) unsigned int*)l, 16, 0, 0);
}
// two HW-transpose LDS reads (4 bf16 each at +32B stride), one wait
__device__ __forceinline__ void tr2(const void* p, uint2& r0, uint2& r1) {
    const __attribute__((address_space(3))) unsigned char* lp =
        (const __attribute__((address_space(3))) unsigned char*)p;
    asm volatile("s_waitcnt lgkmcnt(0)\n\t"
                 "ds_read_b64_tr_b16 %0, %2\n\t"
                 "ds_read_b64_tr_b16 %1, %2 offset:512\n\t"
                 "s_waitcnt lgkmcnt(0)"
                 : "=v"(r0), "=v"(r1) : "v"(lp) : "memory");
}

// ============================================================================
// Kernel 1 (v6): v3b compute structure (1024 blocks, 8h/thread, 17 MAC/out,
// LDS weights) + instruction-lean store path:
//  - Q/K (o<256): per oc: 1 ds_write_b128 into per-wave 1KB tile
//    (idx = h' + 16(wp&3) + 256((wp>>2)&1) + 64(wp>>3); h-contiguous)
//    -> 2 ds_read_b64_tr_b16 -> 1 coalesced uint4 store to [o][h][wp].
//    Any tr j-order quirk permutes d identically for Q and K -> cancels in QK^T.
//  - V (o>=256): direct uint4 store to [o][wp][h].
// Mem-ops/thread: 216 -> 72, all stores 16B.
// ============================================================================
__global__ __launch_bounds__(256) void conv_kernel(
    const float* __restrict__ x, const float* __restrict__ w1,
    const float* __restrict__ w2, unsigned short* __restrict__ y2)
{
    __shared__ float wlds[24 * 16];                  // [oc][0..4]=w1, [5..12]=w2
    __shared__ __align__(16) unsigned char tbuf[4][1024];  // per-wave transpose tile

    const int bid = blockIdx.x;
    const int ht = bid & 1;
    const int g  = (bid >> 1) & 15;
    const int b  = bid >> 5;
    const int tid = threadIdx.x;
    const int wp = tid & 31;
    const int hl = tid >> 5;          // 0..7
    const int h0 = ht * 64 + hl * 8;  // first output h of this thread
    const int lane = tid & 63, wv = tid >> 6;

    // ---- one-time weight staging (block-uniform) ----
    for (int i = tid; i < 384; i += 256) {
        const int oc = i >> 4, ix = i & 15;
        const int o = g * 24 + oc;
        float v = 0.f;
        if (ix < 5)       v = w1[o * 5 + ix];
        else if (ix < 13) v = w2[o * 8 + (ix - 5)];
        wlds[i] = v;
    }

    const float* xbase = x + ((size_t)(b * DIM_ + g) * H_) * DM_ + wp * 8;

    float xr[12][8];
    #pragma unroll
    for (int r = 0; r < 12; ++r) {
        const int hr = h0 - 2 + r;
        if (hr >= 0 && hr < H_) {
            const float4* p = (const float4*)(xbase + (size_t)hr * DM_);
            float4 a = p[0], c = p[1];
            xr[r][0] = a.x; xr[r][1] = a.y; xr[r][2] = a.z; xr[r][3] = a.w;
            xr[r][4] = c.x; xr[r][5] = c.y; xr[r][6] = c.z; xr[r][7] = c.w;
        } else {
            #pragma unroll
            for (int j = 0; j < 8; ++j) xr[r][j] = 0.f;
        }
    }
    __syncthreads();

    // transpose-tile addressing (per wave; same-wave producer/consumer, no barrier)
    unsigned char* tw = &tbuf[wv][0];
    const unsigned wbo = (((lane >> 5) * 8) + 16 * (wp & 3)
                        + 256 * ((wp >> 2) & 1) + 64 * (wp >> 3)) * 2;
    const unsigned rdo = ((lane & 15) + 64 * (lane >> 4)) * 2;
    const int h_s  = ht * 64 + wv * 16 + (lane & 15);   // store h for Q/K path
    const int wp_s = (lane >> 4) * 8;                   // store wp oct base

    for (int oc = 0; oc < 24; ++oc) {
        const int o = g * 24 + oc;
        const float* wo_ = &wlds[oc * 16];
        float w1r[5], w2r[8];
        {
            float4 a = *(const float4*)(wo_);
            float4 c = *(const float4*)(wo_ + 4);
            float4 d = *(const float4*)(wo_ + 8);
            w1r[0] = a.x; w1r[1] = a.y; w1r[2] = a.z; w1r[3] = a.w;
            w1r[4] = c.x;
            w2r[0] = c.y; w2r[1] = c.z; w2r[2] = c.w;
            w2r[3] = d.x; w2r[4] = d.y; w2r[5] = d.z; w2r[6] = d.w;
            w2r[7] = wo_[12];
        }

        float u[12];
        #pragma unroll
        for (int r = 0; r < 12; ++r) {
            float s = w2r[0] * xr[r][0];
            #pragma unroll
            for (int j = 1; j < 8; ++j) s = fmaf(w2r[j], xr[r][j], s);
            u[r] = s;
        }

        float ys[8];
        #pragma unroll
        for (int hh = 0; hh < 8; ++hh) {
            float y = w1r[0] * u[hh];
            #pragma unroll
            for (int t = 1; t < 5; ++t) y = fmaf(w1r[t], u[hh + t], y);
            ys[hh] = y;
        }
        uint4 pk;
        pk.x = cvtpk(ys[0], ys[1]); pk.y = cvtpk(ys[2], ys[3]);
        pk.z = cvtpk(ys[4], ys[5]); pk.w = cvtpk(ys[6], ys[7]);

        if (o >= 256) {
            // V: direct 16B store, layout [o][wp][h]
            *(uint4*)(y2 + ((size_t)(b * C3_ + o) * 32 + wp) * 128 + h0) = pk;
        } else {
            // Q/K: LDS write (h-contiguous) -> 2 tr reads -> coalesced [o][h][wp]
            *(uint4*)(tw + wbo) = pk;
            uint2 r0, r1;
            tr2(tw + rdo, r0, r1);
            *(uint4*)(y2 + ((size_t)(b * C3_ + o) * 128 + h_s) * 32 + wp_s) =
                make_uint4(r0.x, r0.y, r1.x, r1.y);
        }
    }
}

// ============================================================================
// Kernel 2: MFMA attention per (b, ch). Unchanged from round 8 (known-good;
// V read from [o][wp][h], Q/K from [o][h][wp]).
// ============================================================================
__global__ __launch_bounds__(256) void attn_kernel(
    const unsigned short* __restrict__ y2, unsigned short* __restrict__ z)
{
    __shared__ __align__(16) unsigned char sm[40960];

    const int tid = threadIdx.x;
    const int ch = blockIdx.x & 127, b = blockIdx.x >> 7;
    const size_t base = ((size_t)(b * C3_ + ch)) * 4096;
    const uint4* qg = (const uint4*)(y2 + base);
    const uint4* kg = (const uint4*)(y2 + base + 128 * 4096);
    const uint4* vg = (const uint4*)(y2 + base + 256 * 4096);

    #pragma unroll
    for (int r = 0; r < 2; ++r) {
        const int ci  = tid + r * 256;
        const int row = ci >> 2;
        const int c   = ci & 3;
        const int cx  = c ^ ((row >> 1) & 3);
        *(uint4*)(sm + row * 64 + cx * 16)        = qg[ci];
        *(uint4*)(sm + 8192 + row * 64 + cx * 16) = kg[ci];
        const int vd = ci >> 4;
        const int vhc = ci & 15;
        *(uint4*)(sm + 32768 + vd * 256 + ((vhc * 16) ^ ((vd & 7) << 4))) = vg[ci];
    }
    __syncthreads();

    const int l  = tid & 63, wv = tid >> 6;
    const int lm = l & 15,  lk = l >> 4;

    bf16x8 qf[2];
    #pragma unroll
    for (int t = 0; t < 2; ++t) {
        const int q = (wv * 2 + t) * 16 + lm;
        qf[t] = *(const bf16x8*)(sm + q * 64 + ((lk ^ ((q >> 1) & 3)) << 4));
    }
    f32x4 acc[8][2];
    #pragma unroll
    for (int rt = 0; rt < 8; ++rt) {
        acc[rt][0] = 0; acc[rt][1] = 0;
    }
    #pragma unroll
    for (int rt = 0; rt < 8; ++rt) {
        const int kr = rt * 16 + lm;
        bf16x8 kf = *(const bf16x8*)(sm + 8192 + kr * 64 + ((lk ^ ((kr >> 1) & 3)) << 4));
        acc[rt][0] = __builtin_amdgcn_mfma_f32_16x16x32_bf16(kf, qf[0], acc[rt][0], 0, 0, 0);
        acc[rt][1] = __builtin_amdgcn_mfma_f32_16x16x32_bf16(kf, qf[1], acc[rt][1], 0, 0, 0);
    }

    const float Cc = 0.17677669529663687f * 1.4426950408889634f;
    float inv[2];
    #pragma unroll
    for (int t = 0; t < 2; ++t) {
        float m = acc[0][t][0];
        #pragma unroll
        for (int rt = 0; rt < 8; ++rt)
            #pragma unroll
            for (int rg = 0; rg < 4; ++rg) m = fmaxf(m, acc[rt][t][rg]);
        m = fmaxf(m, __shfl_xor(m, 16));
        m = fmaxf(m, __shfl_xor(m, 32));
        float s = 0.f;
        #pragma unroll
        for (int rt = 0; rt < 8; ++rt)
            #pragma unroll
            for (int rg = 0; rg < 4; ++rg) {
                float p = exp2f((acc[rt][t][rg] - m) * Cc);
                acc[rt][t][rg] = p; s += p;
            }
        s += __shfl_xor(s, 16);
        s += __shfl_xor(s, 32);
        inv[t] = 1.0f / s;
    }

    __syncthreads();

    #pragma unroll
    for (int t = 0; t < 2; ++t) {
        const int q = (wv * 2 + t) * 16 + lm;
        #pragma unroll
        for (int rt = 0; rt < 8; ++rt) {
            unsigned u0 = cvtpk(acc[rt][t][0] * inv[t], acc[rt][t][1] * inv[t]);
            unsigned u1 = cvtpk(acc[rt][t][2] * inv[t], acc[rt][t][3] * inv[t]);
            const int kb = rt * 32 + lk * 8;
            *(uint2*)(sm + q * 256 + (kb ^ ((q & 7) << 4))) = make_uint2(u0, u1);
        }
    }
    __syncthreads();

    f32x4 o[2][2];
    o[0][0] = 0; o[0][1] = 0; o[1][0] = 0; o[1][1] = 0;
    #pragma unroll
    for (int kc = 0; kc < 4; ++kc) {
        const int cb = kc * 64 + lk * 16;
        bf16x8 av[2], bp[2];
        #pragma unroll
        for (int dt = 0; dt < 2; ++dt) {
            const int d = dt * 16 + lm;
            av[dt] = *(const bf16x8*)(sm + 32768 + d * 256 + (cb ^ ((d & 7) << 4)));
        }
        #pragma unroll
        for (int t = 0; t < 2; ++t) {
            const int q = (wv * 2 + t) * 16 + lm;
            bp[t] = *(const bf16x8*)(sm + q * 256 + (cb ^ ((q & 7) << 4)));
        }
        #pragma unroll
        for (int dt = 0; dt < 2; ++dt)
            #pragma unroll
            for (int t = 0; t < 2; ++t)
                o[dt][t] = __builtin_amdgcn_mfma_f32_16x16x32_bf16(av[dt], bp[t], o[dt][t], 0, 0, 0);
    }

    const int dd = ch >> 3, nn = ch & 7;
    unsigned short* zb = z + ((size_t)(b * DIM_ + dd)) * (H_ * DM_);
    #pragma unroll
    for (int dt = 0; dt < 2; ++dt)
        #pragma unroll
        for (int t = 0; t < 2; ++t) {
            const int q  = (wv * 2 + t) * 16 + lm;
            const int d0 = dt * 16 + lk * 4;
            unsigned u0 = cvtpk(o[dt][t][0], o[dt][t][1]);
            unsigned u1 = cvtpk(o[dt][t][2], o[dt][t][3]);
            *(uint2*)(zb + (size_t)q * DM_ + nn * 32 + d0) = make_uint2(u0, u1);
        }
}

// ============================================================================
// Kernel 3: W -> bf16 hi/lo split. Unchanged.
// ============================================================================
__global__ __launch_bounds__(256) void prep_w(
    const float* __restrict__ w, unsigned short* __restrict__ wh,
    unsigned short* __restrict__ wl)
{
    const int i = blockIdx.x * 1024 + threadIdx.x * 4;
    float4 v = *(const float4*)(w + i);
    float vv[4] = { v.x, v.y, v.z, v.w };
    unsigned short h[4], lo[4];
    #pragma unroll
    for (int j = 0; j < 4; ++j) {
        h[j] = f2bfu(vv[j]);
        float hf = __uint_as_float(((unsigned)h[j]) << 16);
        lo[j] = f2bfu(vv[j] - hf);
    }
    *(uint2*)(wh + i) = make_uint2((unsigned)h[0] | ((unsigned)h[1] << 16),
                                   (unsigned)h[2] | ((unsigned)h[3] << 16));
    *(uint2*)(wl + i) = make_uint2((unsigned)lo[0] | ((unsigned)lo[1] << 16),
                                   (unsigned)lo[2] | ((unsigned)lo[3] << 16));
}

// ============================================================================
// Kernel 4: MFMA out-projection. Unchanged (known-good).
// ============================================================================
__global__ __launch_bounds__(256) void proj_kernel(
    const unsigned short* __restrict__ zz, const unsigned short* __restrict__ wh,
    const unsigned short* __restrict__ wl, const float* __restrict__ bias,
    float* __restrict__ out)
{
    __shared__ __align__(16) unsigned char sm[65536];   // 2 bufs x 32KB
    const int tid = threadIdx.x;
    const int l = tid & 63, wv = tid >> 6, lm = l & 15, lk = l >> 4;
    const unsigned short* zs = zz + (size_t)blockIdx.x * 32768;

    const int g_off = (tid >> 2) * 256 + (tid & 3) * 8;
    const int lds_wv = wv * 1024;

    const int arow0 = wv * 32 + lm;

    f32x4 acc[2][16];
    #pragma unroll
    for (int t = 0; t < 2; ++t)
        #pragma unroll
        for (int nt = 0; nt < 16; ++nt) acc[t][nt] = 0;

    bf16x8 areg[2][2];

    #pragma unroll
    for (int i = 0; i < 8; ++i) {
        const unsigned short* g = (i < 4 ? wh : wl) + g_off + (i & 3) * 16384;
        gl_lds16(g, sm + i * 4096 + lds_wv);
    }
    #pragma unroll
    for (int t = 0; t < 2; ++t)
        areg[0][t] = *(const bf16x8*)(zs + (size_t)(arow0 + t * 16) * 256 + lk * 8);

    __syncthreads();

    #pragma unroll
    for (int kc = 0; kc < 8; ++kc) {
        const int buf = kc & 1;
        if (kc < 7) {
            #pragma unroll
            for (int i = 0; i < 8; ++i) {
                const unsigned short* g = (i < 4 ? wh : wl) + g_off + (i & 3) * 16384 + (kc + 1) * 32;
                gl_lds16(g, sm + (buf ^ 1) * 32768 + i * 4096 + lds_wv);
            }
            #pragma unroll
            for (int t = 0; t < 2; ++t)
                areg[buf ^ 1][t] = *(const bf16x8*)(zs + (size_t)(arow0 + t * 16) * 256 + (kc + 1) * 32 + lk * 8);
        }
        #pragma unroll
        for (int ph = 0; ph < 2; ++ph)
            #pragma unroll
            for (int nt = 0; nt < 16; ++nt) {
                bf16x8 bf = *(const bf16x8*)(sm + buf * 32768 + ph * 16384 + nt * 1024 + lm * 64 + lk * 16);
                acc[0][nt] = __builtin_amdgcn_mfma_f32_16x16x32_bf16(areg[buf][0], bf, acc[0][nt], 0, 0, 0);
                acc[1][nt] = __builtin_amdgcn_mfma_f32_16x16x32_bf16(areg[buf][1], bf, acc[1][nt], 0, 0, 0);
            }
        __syncthreads();
    }

    float* ob = out + (size_t)blockIdx.x * 32768;
    #pragma unroll
    for (int t = 0; t < 2; ++t)
        #pragma unroll
        for (int nt = 0; nt < 16; ++nt) {
            const float bv = bias[nt * 16 + lm];
            #pragma unroll
            for (int rg = 0; rg < 4; ++rg)
                ob[(size_t)(wv * 32 + t * 16 + lk * 4 + rg) * 256 + nt * 16 + lm] = acc[t][nt][rg] + bv;
        }
}

// ============================================================================
extern "C" void kernel_launch(void* const* d_in, const int* in_sizes, int n_in,
                              void* d_out, int out_size, void* d_ws, size_t ws_size,
                              hipStream_t stream)
{
    const float* x  = (const float*)d_in[0];
    const float* w1 = (const float*)d_in[1];
    const float* w2 = (const float*)d_in[2];
    const float* wo = (const float*)d_in[3];
    const float* wb = (const float*)d_in[4];
    float* out = (float*)d_out;

    unsigned short* y2 = (unsigned short*)d_ws;                    // 100,663,296 B
    unsigned short* zz = y2 + (size_t)B_ * C3_ * H_ * WP_;         // + 33,554,432 B
    unsigned short* wh = y2;                                       // overlays dead y2 (after attn)
    unsigned short* wl = y2 + 65536;

    conv_kernel<<<dim3(1024), dim3(256), 0, stream>>>(x, w1, w2, y2);
    attn_kernel<<<dim3(4096), dim3(256), 0, stream>>>(y2, zz);
    prep_w<<<dim3(64), dim3(256), 0, stream>>>(wo, wh, wl);
    proj_kernel<<<dim3(512), dim3(256), 0, stream>>>(zz, wh, wl, wb, out);
}